// Round 4
// baseline (16802.838 us; speedup 1.0000x reference)
//
#include <hip/hip_runtime.h>

// ---------------------------------------------------------------------------
// StackedBLSTMEmbedding: B=32, T=2000, D=80, H=256/dir, HD=512, O=512
// Round 4 (= round 2 resubmit; GPU acquisition timed out twice, untested).
//   All big activations f16. Stride-2 max-pool fused into layer-1 recurrence.
//   Tier a (ws>=343MB): precomputed f16 gate projections (xg) both layers.
//   Tier b (ws>=212MB): layer-1 xg computed on-the-fly in the recurrence.
//   Tier c (ws>= 81MB): both layers on-the-fly.
// ---------------------------------------------------------------------------

typedef _Float16 h2_t __attribute__((ext_vector_type(2)));

__device__ __forceinline__ float dot2acc(unsigned int w, unsigned int h, float acc) {
  h2_t wv = __builtin_bit_cast(h2_t, w);
  h2_t hv = __builtin_bit_cast(h2_t, h);
#if __has_builtin(__builtin_amdgcn_fdot2)
  return __builtin_amdgcn_fdot2(wv, hv, acc, false);
#else
  return acc + (float)wv[0] * (float)hv[0] + (float)wv[1] * (float)hv[1];
#endif
}

__device__ __forceinline__ float dot8(uint4 w, uint4 h, float acc) {
  acc = dot2acc(w.x, h.x, acc);
  acc = dot2acc(w.y, h.y, acc);
  acc = dot2acc(w.z, h.z, acc);
  acc = dot2acc(w.w, h.w, acc);
  return acc;
}

// Pack fp32 W[1024][K] -> f16 uint4 Wp[k8][1024] (k8 = k/8).
__global__ __launch_bounds__(256) void pack_w(const float* __restrict__ W,
                                              uint4* __restrict__ Wp, int K) {
  const int idx = blockIdx.x * 256 + threadIdx.x;
  const int total = (K >> 3) << 10;
  if (idx >= total) return;
  const int g = idx & 1023;
  const int k8 = idx >> 10;
  const float* src = W + (size_t)g * K + k8 * 8;
  h2_t p0, p1, p2, p3;
  p0[0] = (_Float16)src[0]; p0[1] = (_Float16)src[1];
  p1[0] = (_Float16)src[2]; p1[1] = (_Float16)src[3];
  p2[0] = (_Float16)src[4]; p2[1] = (_Float16)src[5];
  p3[0] = (_Float16)src[6]; p3[1] = (_Float16)src[7];
  uint4 o;
  o.x = __builtin_bit_cast(unsigned int, p0);
  o.y = __builtin_bit_cast(unsigned int, p1);
  o.z = __builtin_bit_cast(unsigned int, p2);
  o.w = __builtin_bit_cast(unsigned int, p3);
  Wp[(size_t)k8 * 1024 + g] = o;
}

__global__ __launch_bounds__(256) void pack_flat(const float* __restrict__ src,
                                                 _Float16* __restrict__ dst, int n) {
  const int i = blockIdx.x * 256 + threadIdx.x;
  if (i < n) dst[i] = (_Float16)src[i];
}

__global__ __launch_bounds__(256) void zero16(uint4* __restrict__ p, int n16) {
  const int i = blockIdx.x * 256 + threadIdx.x;
  if (i < n16) { uint4 z; z.x = z.y = z.z = z.w = 0u; p[i] = z; }
}

// C[M][N] = A[M][K](f16) @ B[N][K](f32)^T + bias. M%128==0, N%64==0, K%16==0.
template <typename CT>
__global__ __launch_bounds__(256) void gemm_f16a(
    const _Float16* __restrict__ A, const float* __restrict__ B,
    const float* __restrict__ bias, CT* __restrict__ C,
    int M, int N, int K) {
  __shared__ float As[16][128];
  __shared__ float Bs[16][64];
  const int tid = threadIdx.x;
  const int m0 = blockIdx.y * 128, n0 = blockIdx.x * 64;
  const int ra = tid >> 1;            // 0..127
  const int ca = (tid & 1) * 8;       // 0 or 8 (halves)
  const int rb = tid >> 2;            // 0..63
  const int cb = (tid & 3) * 4;       // 0,4,8,12
  const int ty = tid >> 4;            // 0..15 -> 8 rows
  const int tx = tid & 15;            // 0..15 -> 4 cols
  float acc[8][4] = {};
  for (int k0 = 0; k0 < K; k0 += 16) {
    const uint4 av = *reinterpret_cast<const uint4*>(&A[(size_t)(m0 + ra) * K + k0 + ca]);
    const float4 b0 = *reinterpret_cast<const float4*>(&B[(size_t)(n0 + rb) * K + k0 + cb]);
    __syncthreads();
    {
      h2_t p0 = __builtin_bit_cast(h2_t, av.x);
      h2_t p1 = __builtin_bit_cast(h2_t, av.y);
      h2_t p2 = __builtin_bit_cast(h2_t, av.z);
      h2_t p3 = __builtin_bit_cast(h2_t, av.w);
      As[ca + 0][ra] = (float)p0[0]; As[ca + 1][ra] = (float)p0[1];
      As[ca + 2][ra] = (float)p1[0]; As[ca + 3][ra] = (float)p1[1];
      As[ca + 4][ra] = (float)p2[0]; As[ca + 5][ra] = (float)p2[1];
      As[ca + 6][ra] = (float)p3[0]; As[ca + 7][ra] = (float)p3[1];
    }
    Bs[cb + 0][rb] = b0.x; Bs[cb + 1][rb] = b0.y;
    Bs[cb + 2][rb] = b0.z; Bs[cb + 3][rb] = b0.w;
    __syncthreads();
#pragma unroll
    for (int kk = 0; kk < 16; ++kk) {
      const float4 av0 = *reinterpret_cast<const float4*>(&As[kk][ty * 8]);
      const float4 av1 = *reinterpret_cast<const float4*>(&As[kk][ty * 8 + 4]);
      const float4 bv  = *reinterpret_cast<const float4*>(&Bs[kk][tx * 4]);
      const float a[8] = {av0.x, av0.y, av0.z, av0.w, av1.x, av1.y, av1.z, av1.w};
      const float bb[4] = {bv.x, bv.y, bv.z, bv.w};
#pragma unroll
      for (int i = 0; i < 8; ++i)
#pragma unroll
        for (int j = 0; j < 4; ++j) acc[i][j] += a[i] * bb[j];
    }
  }
  const float4 bias4 = *reinterpret_cast<const float4*>(&bias[n0 + tx * 4]);
  const float bb[4] = {bias4.x, bias4.y, bias4.z, bias4.w};
#pragma unroll
  for (int i = 0; i < 8; ++i) {
    const size_t cidx = (size_t)(m0 + ty * 8 + i) * N + n0 + tx * 4;
    if constexpr (sizeof(CT) == 2) {
      h2_t lo, hi;
      lo[0] = (_Float16)(acc[i][0] + bb[0]); lo[1] = (_Float16)(acc[i][1] + bb[1]);
      hi[0] = (_Float16)(acc[i][2] + bb[2]); hi[1] = (_Float16)(acc[i][3] + bb[3]);
      uint2 st;
      st.x = __builtin_bit_cast(unsigned int, lo);
      st.y = __builtin_bit_cast(unsigned int, hi);
      *reinterpret_cast<uint2*>(&C[cidx]) = st;
    } else {
      float4 o;
      o.x = acc[i][0] + bb[0]; o.y = acc[i][1] + bb[1];
      o.z = acc[i][2] + bb[2]; o.w = acc[i][3] + bb[3];
      *reinterpret_cast<float4*>(&C[cidx]) = o;
    }
  }
}

// One block per (batch, dir); thread u owns hidden unit u (gate rows u,u+256,u+512,u+768).
// ONFLY: gates = bias + Wih@x_t (from packed xh) + Whh@h;  else read precomputed xg (f16).
// POOL:  emit f16 max(h_2p, h_2p+1) into [B][T/2][512] (masked tail -> max(h,0));
// else:  emit f16 h into [B][T][512].  Rows beyond len stay 0 (pre-zeroed).
template <int ONFLY, int POOL>
__global__ __launch_bounds__(256) void lstm_bidir(
    const _Float16* __restrict__ xg_f, const _Float16* __restrict__ xg_b,
    const uint4* __restrict__ xh, int kx8,
    const uint4* __restrict__ wih_f, const uint4* __restrict__ wih_b,
    const float* __restrict__ bias_f, const float* __restrict__ bias_b,
    const uint4* __restrict__ whh_f, const uint4* __restrict__ whh_b,
    _Float16* __restrict__ outp, const int* __restrict__ x_len,
    int lenshift, int T) {
  const int b = blockIdx.x;
  const int dir = blockIdx.y;
  const int u = threadIdx.x;
  const int len = x_len[b] >> lenshift;
  const _Float16* xg = dir ? xg_b : xg_f;
  const uint4* wih = dir ? wih_b : wih_f;
  const float* bias = dir ? bias_b : bias_f;
  const uint4* whh0 = (dir ? whh_b : whh_f) + u;
  const int col0 = dir ? 256 : 0;
  float bi = 0.f, bff = 0.f, bg = 0.f, bo = 0.f;
  if (ONFLY) {
    bi = bias[u]; bff = bias[u + 256]; bg = bias[u + 512]; bo = bias[u + 768];
  }
  __shared__ __align__(16) _Float16 hbuf[2][256];
  hbuf[0][u] = (_Float16)0.f;
  float c = 0.f, hpend = 0.f;
  __syncthreads();
  int cur = 0;
  const int Tp = T >> 1;
  for (int s = 0; s < len; ++s) {
    const int t = dir ? (len - 1 - s) : s;
    float ai, af, ag, ao;
    if (ONFLY) {
      ai = bi; af = bff; ag = bg; ao = bo;
      const uint4* xr = xh + ((size_t)b * T + t) * kx8;
      const uint4* wi = wih + u;
#pragma unroll 2
      for (int k8 = 0; k8 < kx8; ++k8) {
        const uint4 xv = xr[k8];
        ai = dot8(wi[0],   xv, ai);
        af = dot8(wi[256], xv, af);
        ag = dot8(wi[512], xv, ag);
        ao = dot8(wi[768], xv, ao);
        wi += 1024;
      }
    } else {
      const _Float16* xp = xg + ((size_t)b * T + t) * 1024 + u;
      ai = (float)xp[0]; af = (float)xp[256]; ag = (float)xp[512]; ao = (float)xp[768];
    }
    const uint4* hp = reinterpret_cast<const uint4*>(hbuf[cur]);
#pragma unroll 4
    for (int k8 = 0; k8 < 32; ++k8) {
      const uint4 hv = hp[k8];
      const uint4* wr = whh0 + (k8 << 10);
      ai = dot8(wr[0],   hv, ai);
      af = dot8(wr[256], hv, af);
      ag = dot8(wr[512], hv, ag);
      ao = dot8(wr[768], hv, ao);
    }
    const float gi = 1.f / (1.f + expf(-ai));
    const float gf = 1.f / (1.f + expf(-af));
    const float gg = tanhf(ag);
    const float go = 1.f / (1.f + expf(-ao));
    c = gf * c + gi * gg;
    const float h = go * tanhf(c);
    if (POOL) {
      if (dir == 0) {
        if (t & 1) outp[((size_t)b * Tp + (t >> 1)) * 512 + col0 + u] = (_Float16)fmaxf(hpend, h);
        else hpend = h;
      } else {
        if (t & 1) hpend = h;
        else outp[((size_t)b * Tp + (t >> 1)) * 512 + col0 + u] = (_Float16)fmaxf(h, hpend);
      }
    } else {
      outp[((size_t)b * T + t) * 512 + col0 + u] = (_Float16)h;
    }
    hbuf[cur ^ 1][u] = (_Float16)h;
    cur ^= 1;
    __syncthreads();
  }
  if (POOL && dir == 0 && (len & 1)) {
    outp[((size_t)b * Tp + ((len - 1) >> 1)) * 512 + col0 + u] = (_Float16)fmaxf(hpend, 0.f);
  }
}

__global__ void lens_k(const int* __restrict__ x_len, float* __restrict__ dst) {
  const int b = threadIdx.x;
  if (b < 32) dst[b] = (float)(x_len[b] >> 1);
}

extern "C" void kernel_launch(void* const* d_in, const int* in_sizes, int n_in,
                              void* d_out, int out_size, void* d_ws, size_t ws_size,
                              hipStream_t stream) {
  (void)in_sizes; (void)n_in; (void)out_size;
  const float* x     = (const float*)d_in[0];
  const int*   x_len = (const int*)d_in[1];
  const float* Wih1f = (const float*)d_in[2];
  const float* Whh1f = (const float*)d_in[3];
  const float* b1f   = (const float*)d_in[4];
  const float* Wih1b = (const float*)d_in[5];
  const float* Whh1b = (const float*)d_in[6];
  const float* b1b   = (const float*)d_in[7];
  const float* Wih2f = (const float*)d_in[8];
  const float* Whh2f = (const float*)d_in[9];
  const float* b2f   = (const float*)d_in[10];
  const float* Wih2b = (const float*)d_in[11];
  const float* Whh2b = (const float*)d_in[12];
  const float* b2b   = (const float*)d_in[13];
  const float* Wlin  = (const float*)d_in[14];
  const float* blin  = (const float*)d_in[15];
  float* outF = (float*)d_out;

  char* w = (char*)d_ws;
  size_t off = 0;
  auto alloc = [&](size_t bytes) -> void* {
    void* p = w + off;
    off += (bytes + 255) & ~(size_t)255;
    return p;
  };
  uint4* wp_hh1f = (uint4*)alloc(524288);
  uint4* wp_hh1b = (uint4*)alloc(524288);
  uint4* wp_hh2f = (uint4*)alloc(524288);
  uint4* wp_hh2b = (uint4*)alloc(524288);
  uint4* wp_ih1f = (uint4*)alloc(163840);
  uint4* wp_ih1b = (uint4*)alloc(163840);
  uint4* wp_ih2f = (uint4*)alloc(1048576);
  uint4* wp_ih2b = (uint4*)alloc(1048576);
  _Float16* x_h    = (_Float16*)alloc(10240000);   // 32*2000*80
  _Float16* pooled = (_Float16*)alloc(32768000);   // 32*1000*512 (f16)
  _Float16* out2   = (_Float16*)alloc(32768000);   // 32*1000*512 (f16), contiguous after pooled
  const size_t var_off = off;
  _Float16* varr = (_Float16*)(w + var_off);
  _Float16* xg1f = varr;                  // 32*2000*1024 f16 = 131,072,000 B
  _Float16* xg1b = varr + 65536000;
  _Float16* xg2f = varr;                  // 32*1000*1024 f16 = 65,536,000 B (reuses xg1)
  _Float16* xg2b = varr + 32768000;

  int tier;
  if (ws_size >= var_off + 262144000ULL)      tier = 0;  // precomputed xg both layers
  else if (ws_size >= var_off + 131072000ULL) tier = 1;  // layer-1 on-the-fly
  else                                        tier = 2;  // both on-the-fly

  // Pack all weights (cheap, unconditional)
  pack_w<<<128, 256, 0, stream>>>(Whh1f, wp_hh1f, 256);
  pack_w<<<128, 256, 0, stream>>>(Whh1b, wp_hh1b, 256);
  pack_w<<<128, 256, 0, stream>>>(Whh2f, wp_hh2f, 256);
  pack_w<<<128, 256, 0, stream>>>(Whh2b, wp_hh2b, 256);
  pack_w<<<40, 256, 0, stream>>>(Wih1f, wp_ih1f, 80);
  pack_w<<<40, 256, 0, stream>>>(Wih1b, wp_ih1b, 80);
  pack_w<<<256, 256, 0, stream>>>(Wih2f, wp_ih2f, 512);
  pack_w<<<256, 256, 0, stream>>>(Wih2b, wp_ih2b, 512);
  pack_flat<<<20000, 256, 0, stream>>>(x, x_h, 5120000);
  // zero pooled + out2 (contiguous, 65,536,000 B = 4,096,000 uint4)
  zero16<<<16000, 256, 0, stream>>>((uint4*)pooled, 4096000);

  // ---- Layer 1 (fused pool) ----
  if (tier == 0) {
    gemm_f16a<_Float16><<<dim3(16, 500), 256, 0, stream>>>(x_h, Wih1f, b1f, xg1f, 64000, 1024, 80);
    gemm_f16a<_Float16><<<dim3(16, 500), 256, 0, stream>>>(x_h, Wih1b, b1b, xg1b, 64000, 1024, 80);
    lstm_bidir<0, 1><<<dim3(32, 2), 256, 0, stream>>>(
        xg1f, xg1b, nullptr, 0, nullptr, nullptr, nullptr, nullptr,
        wp_hh1f, wp_hh1b, pooled, x_len, 0, 2000);
  } else {
    lstm_bidir<1, 1><<<dim3(32, 2), 256, 0, stream>>>(
        nullptr, nullptr, (const uint4*)x_h, 10, wp_ih1f, wp_ih1b, b1f, b1b,
        wp_hh1f, wp_hh1b, pooled, x_len, 0, 2000);
  }

  // ---- Layer 2 ----
  if (tier <= 1) {
    gemm_f16a<_Float16><<<dim3(16, 250), 256, 0, stream>>>(pooled, Wih2f, b2f, xg2f, 32000, 1024, 512);
    gemm_f16a<_Float16><<<dim3(16, 250), 256, 0, stream>>>(pooled, Wih2b, b2b, xg2b, 32000, 1024, 512);
    lstm_bidir<0, 0><<<dim3(32, 2), 256, 0, stream>>>(
        xg2f, xg2b, nullptr, 0, nullptr, nullptr, nullptr, nullptr,
        wp_hh2f, wp_hh2b, out2, x_len, 1, 1000);
  } else {
    lstm_bidir<1, 0><<<dim3(32, 2), 256, 0, stream>>>(
        nullptr, nullptr, (const uint4*)pooled, 64, wp_ih2f, wp_ih2b, b2f, b2b,
        wp_hh2f, wp_hh2b, out2, x_len, 1, 1000);
  }

  // ---- Final linear + lens ----
  gemm_f16a<float><<<dim3(8, 250), 256, 0, stream>>>(out2, Wlin, blin, outF, 32000, 512, 512);
  lens_k<<<1, 32, 0, stream>>>(x_len, outF + (size_t)16384000);
}